// Round 7
// baseline (499.232 us; speedup 1.0000x reference)
//
#include <hip/hip_runtime.h>
#include <hip/hip_bf16.h>

#define B_ 4
#define T_ 2048
#define C_ 1024
#define H_ 16
#define D_ 64
#define M_ (B_*T_)   // 8192

typedef unsigned short ushort;
typedef __attribute__((ext_vector_type(8))) short short8;
typedef __attribute__((ext_vector_type(8))) unsigned short ushort8;
typedef __attribute__((ext_vector_type(4))) float floatx4;
typedef __attribute__((ext_vector_type(4))) unsigned int uintx4;

static __device__ __forceinline__ float bf2f(ushort u) {
    unsigned int x = ((unsigned int)u) << 16;
    return __builtin_bit_cast(float, x);
}
static __device__ __forceinline__ ushort f2bf(float f) {
    unsigned int x = __builtin_bit_cast(unsigned int, f);
    unsigned int r = (x + 0x7fffu + ((x >> 16) & 1u)) >> 16;
    return (ushort)r;
}

typedef const __attribute__((address_space(1))) unsigned int gu32;
typedef __attribute__((address_space(3))) unsigned int lu32;
static __device__ __forceinline__ void glds16(const void* g, void* l) {
    __builtin_amdgcn_global_load_lds((gu32*)g, (lu32*)l, 16, 0, 0);
}

// ---------------- LayerNorm: fp32 in -> bf16 out ----------------
__global__ __launch_bounds__(256) void ln_kernel(
    const float* __restrict__ x, const float* __restrict__ g,
    const float* __restrict__ be, ushort* __restrict__ out)
{
    int row = blockIdx.x;
    int tid = threadIdx.x;
    const float* xr = x + (size_t)row * C_;
    float v[4];
    float s = 0.f, s2 = 0.f;
#pragma unroll
    for (int i = 0; i < 4; i++) {
        float t = xr[tid + i * 256];
        v[i] = t; s += t; s2 += t * t;
    }
#pragma unroll
    for (int off = 32; off; off >>= 1) {
        s  += __shfl_down(s, off);
        s2 += __shfl_down(s2, off);
    }
    __shared__ float rs[4], rs2[4];
    __shared__ float smu, srstd;
    int w = tid >> 6;
    if ((tid & 63) == 0) { rs[w] = s; rs2[w] = s2; }
    __syncthreads();
    if (tid == 0) {
        float ts  = rs[0] + rs[1] + rs[2] + rs[3];
        float ts2 = rs2[0] + rs2[1] + rs2[2] + rs2[3];
        float mu  = ts * (1.f / C_);
        float var = ts2 * (1.f / C_) - mu * mu;
        smu = mu; srstd = rsqrtf(var + 1e-5f);
    }
    __syncthreads();
    float mu = smu, r = srstd;
#pragma unroll
    for (int i = 0; i < 4; i++) {
        int c = tid + i * 256;
        out[(size_t)row * C_ + c] = f2bf((v[i] - mu) * r * g[c] + be[c]);
    }
}

// ------------- transpose + fp32->bf16 convert: in (R x Cn) -> out (Cn x R) -------------
__global__ __launch_bounds__(256) void transpose_conv(
    const float* __restrict__ in, ushort* __restrict__ out,
    int R, int Cn, long long in_bstride, long long out_bstride)
{
    __shared__ float tile[32][33];
    const float* ip = in + (size_t)blockIdx.z * in_bstride;
    ushort* op = out + (size_t)blockIdx.z * out_bstride;
    int tx = threadIdx.x;          // 32
    int ty = threadIdx.y;          // 8
    int c0 = blockIdx.x * 32, r0 = blockIdx.y * 32;
#pragma unroll
    for (int i = 0; i < 32; i += 8) {
        tile[ty + i][tx] = ip[(size_t)(r0 + ty + i) * Cn + c0 + tx];
    }
    __syncthreads();
#pragma unroll
    for (int i = 0; i < 32; i += 8) {
        int oc = c0 + ty + i;
        int orr = r0 + tx;
        op[(size_t)oc * R + orr] = f2bf(tile[tx][ty + i]);
    }
}

// ------------- V transpose: qkv V block -> VtG[(h*256 + 4*d + b)*2048 + t] -------------
__global__ __launch_bounds__(256) void vtrans_kernel(
    const ushort* __restrict__ qkv, ushort* __restrict__ VtG)
{
    int bh = blockIdx.y;
    int b = bh >> 4, h = bh & 15;
    int j0 = blockIdx.x * 64;
    int tid = threadIdx.x;
    __shared__ unsigned int X[64 * 33];
    const ushort* Vg = qkv + (size_t)(b * T_) * 3072 + 2048 + h * 64;
#pragma unroll
    for (int it = 0; it < 2; it++) {
        int j = (tid >> 3) + it * 32;
        int dp = (tid & 7) * 4;
        uintx4 val = *(const uintx4*)(Vg + (size_t)(j0 + j) * 3072 + dp * 2);
#pragma unroll
        for (int k = 0; k < 4; k++) X[j * 33 + dp + k] = val[k];
    }
    __syncthreads();
    int dp = tid >> 3, jc = tid & 7;
    unsigned int v[8];
#pragma unroll
    for (int jj = 0; jj < 8; jj++) v[jj] = X[(jc * 8 + jj) * 33 + dp];
    ushort8 lo, hi;
#pragma unroll
    for (int jj = 0; jj < 8; jj++) {
        lo[jj] = (ushort)(v[jj] & 0xffffu);
        hi[jj] = (ushort)(v[jj] >> 16);
    }
    size_t r0 = ((size_t)(h * 256 + 4 * (2 * dp) + b)) * T_ + j0 + jc * 8;
    size_t r1 = ((size_t)(h * 256 + 4 * (2 * dp + 1) + b)) * T_ + j0 + jc * 8;
    *(ushort8*)&VtG[r0] = lo;
    *(ushort8*)&VtG[r1] = hi;
}

// ============ 128x128 BK=32 3-buffer GEMM, superrow-swizzled LDS (conflict-free) ============
// 4 waves (2Mx2N). LDS 3x(8+8)KB = 48KB -> 3 blocks/CU. Layout: 128-B superrow holds 2 m-rows;
// global (row,chunk16) stored at superrow=row>>1, slot=(((row&1)<<2)|chunk)^(superrow&7).
// Write stays glds16-linear via pre-swizzled per-lane GLOBAL source (T2/m173); read uses the
// same involution -> <=2-way bank aliasing (free). Rotation: tile t reads s0, stage(t+2)->s2
// (freed end of t-1, no drain); ONE vmcnt(4) + ONE barrier per tile.
template<bool OUTBF16, bool BIAS, bool RELU, bool RESID>
__global__ __launch_bounds__(256, 3) void gemm128_kernel(
    const ushort* __restrict__ A,
    const ushort* __restrict__ Bt,
    const float* __restrict__ bias,
    const float* __restrict__ resid,
    void* __restrict__ Cout,
    int Mdim, int Ndim, int K)
{
    __shared__ ushort As[3][128 * 32];
    __shared__ ushort Bs[3][128 * 32];

    // XCD-aware bijective swizzle (nwg % 8 == 0 at all call sites)
    int gridX = gridDim.x;
    int nwg = gridX * gridDim.y;
    int bid = blockIdx.y * gridX + blockIdx.x;
    int cpx = nwg >> 3;
    int swz = (bid & 7) * cpx + (bid >> 3);
    int bx = swz % gridX, by = swz / gridX;
    int m0 = by * 128, n0 = bx * 128;

    int tid = threadIdx.x;
    int wave = tid >> 6, lane = tid & 63;
    int quad = lane >> 4, l16 = lane & 15;
    int wm = (wave >> 1) * 64, wn = (wave & 1) * 64;

    // stage-side pre-swizzled source mapping: lane ln fills LDS slot (sr=ln>>3, slot=ln&7);
    // content must be global(row = 2*sr + (e>>2), chunk = e&3), e = slot ^ sr.
    int e_st = (lane & 7) ^ (lane >> 3);
    int srow_off = 2 * (lane >> 3) + (e_st >> 2);  // row offset within 16-row group
    int schunk = e_st & 3;                          // 16B-chunk within the row's 64B

    floatx4 acc[4][4] = {};
    int nt = K >> 5;

    auto stage = [&](int t, int sb) {
        int k0 = t << 5;
#pragma unroll
        for (int it = 0; it < 2; it++) {
            int rb = (it * 4 + wave) * 16;
            glds16(A + (size_t)(m0 + rb + srow_off) * K + k0 + schunk * 8, &As[sb][rb * 32]);
        }
#pragma unroll
        for (int it = 0; it < 2; it++) {
            int rb = (it * 4 + wave) * 16;
            glds16(Bt + (size_t)(n0 + rb + srow_off) * K + k0 + schunk * 8, &Bs[sb][rb * 32]);
        }
    };

    // read-side offset for (row r, chunk=quad), in ushort elements
    auto rdoff = [&](int r) -> int {
        int e = ((r & 1) << 2) | quad;
        return (r >> 1) * 64 + ((e ^ ((r >> 1) & 7)) * 8);
    };

    // prologue: tiles 0,1 into slots 0,1; counted wait for tile 0 only (tile 1 in flight)
    stage(0, 0);
    stage(1, 1);
    asm volatile("s_waitcnt vmcnt(4)" ::: "memory");
    __builtin_amdgcn_s_barrier();
    asm volatile("" ::: "memory");

    int s0 = 0, s1 = 1, s2 = 2;
    for (int t = 0; t < nt; ++t) {
        // ---- 8 fragment reads (compiler inserts counted lgkmcnt before MFMAs) ----
        short8 af[4], bfv[4];
#pragma unroll
        for (int mi = 0; mi < 4; mi++)
            af[mi] = *(const short8*)&As[s0][rdoff(wm + mi * 16 + l16)];
#pragma unroll
        for (int ni = 0; ni < 4; ni++)
            bfv[ni] = *(const short8*)&Bs[s0][rdoff(wn + ni * 16 + l16)];
        // ---- stage tile t+2 into slot s2 (freed at end of tile t-1; no drain needed) ----
        bool pf = (t + 2 < nt);
        if (pf) stage(t + 2, s2);
        // ---- 16 MFMA ----
        __builtin_amdgcn_s_setprio(1);
#pragma unroll
        for (int mi = 0; mi < 4; mi++)
#pragma unroll
            for (int ni = 0; ni < 4; ni++)
                acc[mi][ni] = __builtin_amdgcn_mfma_f32_16x16x32_bf16(
                    af[mi], bfv[ni], acc[mi][ni], 0, 0, 0);
        __builtin_amdgcn_s_setprio(0);
        // ---- one counted wait + one barrier per K-tile ----
        if (pf) asm volatile("s_waitcnt vmcnt(4)" ::: "memory");   // t+1 resident; t+2 in flight
        else    asm volatile("s_waitcnt vmcnt(0)" ::: "memory");
        __builtin_amdgcn_s_barrier();
        asm volatile("" ::: "memory");
        int tmp = s0; s0 = s1; s1 = s2; s2 = tmp;
    }

    // epilogue
    int r4 = quad * 4;
#pragma unroll
    for (int mi = 0; mi < 4; mi++) {
#pragma unroll
        for (int ni = 0; ni < 4; ni++) {
#pragma unroll
            for (int r = 0; r < 4; r++) {
                int gm = m0 + wm + mi * 16 + r4 + r;
                int gn = n0 + wn + ni * 16 + l16;
                float v = acc[mi][ni][r];
                if (BIAS)  v += bias[gn];
                if (RESID) v += resid[(size_t)gm * Ndim + gn];
                if (RELU)  v = fmaxf(v, 0.f);
                if (OUTBF16) ((ushort*)Cout)[(size_t)gm * Ndim + gn] = f2bf(v);
                else         ((float*)Cout)[(size_t)gm * Ndim + gn] = v;
            }
        }
    }
}

// ============ 3-buffer rotating bf16 MFMA GEMM (R5-proven): BM=256, BN=128, BK=64 ============
template<bool OUTBF16, bool BIAS, bool RELU, bool RESID>
__global__ __launch_bounds__(512, 2) void gemm3b_kernel(
    const ushort* __restrict__ A,
    const ushort* __restrict__ Bt,
    const float* __restrict__ bias,
    const float* __restrict__ resid,
    void* __restrict__ Cout,
    int Mdim, int Ndim, int K)
{
    __shared__ ushort As[3][256 * 64];
    __shared__ ushort Bs[3][128 * 64];

    int gridX = gridDim.x;
    int nwg = gridX * gridDim.y;
    int bid = blockIdx.y * gridX + blockIdx.x;
    int cpx = nwg >> 3;
    int swz = (bid & 7) * cpx + (bid >> 3);
    int bx = swz % gridX, by = swz / gridX;
    int m0 = by * 256, n0 = bx * 128;

    int tid = threadIdx.x;
    int wave = tid >> 6, lane = tid & 63;
    int quad = lane >> 4, l16 = lane & 15;
    int wr = wave >> 1, wc = wave & 1;
    int wm = wr * 64, wn = wc * 64;
    int lrow = lane >> 3;
    int lchunk = (lane & 7) ^ (lrow & 7);

    floatx4 acc[4][4] = {};
    int nt = K >> 6;

    auto stage = [&](int t, int sb) {
        int k0 = t << 6;
#pragma unroll
        for (int it = 0; it < 4; it++) {
            int rb = it * 64 + wave * 8;
            glds16(A + (size_t)(m0 + rb + lrow) * K + k0 + lchunk * 8, &As[sb][rb * 64]);
        }
#pragma unroll
        for (int it = 0; it < 2; it++) {
            int rb = it * 64 + wave * 8;
            glds16(Bt + (size_t)(n0 + rb + lrow) * K + k0 + lchunk * 8, &Bs[sb][rb * 64]);
        }
    };

    stage(0, 0);
    stage(1, 1);
    asm volatile("s_waitcnt vmcnt(6)" ::: "memory");
    __builtin_amdgcn_s_barrier();
    asm volatile("" ::: "memory");

    int s0 = 0, s1 = 1, s2 = 2;
    for (int t = 0; t < nt; ++t) {
        short8 af[4][2], bfv[4][2];
#pragma unroll
        for (int kk = 0; kk < 2; kk++) {
            int c = kk * 4 + quad;
#pragma unroll
            for (int mi = 0; mi < 4; mi++) {
                int r = wm + mi * 16 + l16;
                af[mi][kk] = *(const short8*)&As[s0][r * 64 + ((c ^ (r & 7)) * 8)];
            }
#pragma unroll
            for (int ni = 0; ni < 4; ni++) {
                int r = wn + ni * 16 + l16;
                bfv[ni][kk] = *(const short8*)&Bs[s0][r * 64 + ((c ^ (r & 7)) * 8)];
            }
        }
        bool pf = (t + 2 < nt);
        if (pf) stage(t + 2, s2);
        __builtin_amdgcn_s_setprio(1);
#pragma unroll
        for (int kk = 0; kk < 2; kk++)
#pragma unroll
            for (int mi = 0; mi < 4; mi++)
#pragma unroll
                for (int ni = 0; ni < 4; ni++)
                    acc[mi][ni] = __builtin_amdgcn_mfma_f32_16x16x32_bf16(
                        af[mi][kk], bfv[ni][kk], acc[mi][ni], 0, 0, 0);
        __builtin_amdgcn_s_setprio(0);
        if (pf) asm volatile("s_waitcnt vmcnt(6)" ::: "memory");
        else    asm volatile("s_waitcnt vmcnt(0)" ::: "memory");
        __builtin_amdgcn_s_barrier();
        asm volatile("" ::: "memory");
        int tmp = s0; s0 = s1; s1 = s2; s2 = tmp;
    }

    int r4 = quad * 4;
#pragma unroll
    for (int mi = 0; mi < 4; mi++) {
#pragma unroll
        for (int ni = 0; ni < 4; ni++) {
#pragma unroll
            for (int r = 0; r < 4; r++) {
                int gm = m0 + wm + mi * 16 + r4 + r;
                int gn = n0 + wn + ni * 16 + l16;
                float v = acc[mi][ni][r];
                if (BIAS)  v += bias[gn];
                if (RESID) v += resid[(size_t)gm * Ndim + gn];
                if (RELU)  v = fmaxf(v, 0.f);
                if (OUTBF16) ((ushort*)Cout)[(size_t)gm * Ndim + gn] = f2bf(v);
                else         ((float*)Cout)[(size_t)gm * Ndim + gn] = v;
            }
        }
    }
}

// ---------------- causal flash attention: XCD-swizzled, dbuf glds, static-max softmax ----------------
__global__ __launch_bounds__(256, 2) void attn_kernel(
    const ushort* __restrict__ qkv,
    const ushort* __restrict__ VtG,   // (h*256 + 4*d + b)*2048 + t
    ushort* __restrict__ attnb)
{
    const int LD = 3072;
    int bid = blockIdx.x;
    int bh = (bid & 7) * 8 + ((bid >> 3) & 7);
    int qt = 15 - (bid >> 6);
    int b = bh >> 4, h = bh & 15;
    int t0 = qt * 128;
    int tid = threadIdx.x;
    int wave = tid >> 6, lane = tid & 63;
    int quad = lane >> 4, l16 = lane & 15;

    __shared__ ushort Ks[2][64 * 64];
    __shared__ ushort Vt[2][64 * 64];
    __shared__ ushort Ps[4][32 * 72];

    const ushort* Qg = qkv + (size_t)(b * T_) * LD + h * 64;
    const ushort* Kg = Qg + 1024;
    const ushort* VtB = VtG + (size_t)(h * 256 + b) * T_;

    int qrow_base = t0 + wave * 32;
    int lrow = lane >> 3;
    int lchunk = (lane & 7) ^ (lrow & 7);

    short8 qa[2][2];
#pragma unroll
    for (int mt = 0; mt < 2; mt++) {
        const ushort* qp = Qg + (size_t)(qrow_base + mt * 16 + l16) * LD + quad * 8;
        ushort8 q0 = *(const ushort8*)qp;
        ushort8 q1 = *(const ushort8*)(qp + 32);
        ushort8 a0, a1;
#pragma unroll
        for (int d = 0; d < 8; d++) {
            a0[d] = f2bf(bf2f(q0[d]) * 0.03125f);
            a1[d] = f2bf(bf2f(q1[d]) * 0.03125f);
        }
        qa[mt][0] = __builtin_bit_cast(short8, a0);
        qa[mt][1] = __builtin_bit_cast(short8, a1);
    }

    float l_part[2][4];
    floatx4 o_acc[2][4];
#pragma unroll
    for (int mt = 0; mt < 2; mt++)
#pragma unroll
        for (int r = 0; r < 4; r++) {
            l_part[mt][r] = 0.f;
            o_acc[mt][r] = floatx4{0.f, 0.f, 0.f, 0.f};
        }

    int nIter = t0 / 64 + 2;

#pragma unroll
    for (int it = 0; it < 2; it++) {
        int rb = (wave * 2 + it) * 8;
        int r = rb + lrow;
        glds16(Kg  + (size_t)r * LD + lchunk * 8, &Ks[0][rb * 64]);
        glds16(VtB + (size_t)r * (4 * T_) + lchunk * 8, &Vt[0][rb * 64]);
    }

    for (int ii = 0; ii < nIter; ii++) {
        int s0 = ii * 64;
        int buf = ii & 1;
        __syncthreads();
        if (ii + 1 < nIter) {
            int sn = s0 + 64;
#pragma unroll
            for (int it = 0; it < 2; it++) {
                int rb = (wave * 2 + it) * 8;
                int r = rb + lrow;
                glds16(Kg  + (size_t)(sn + r) * LD + lchunk * 8, &Ks[buf ^ 1][rb * 64]);
                glds16(VtB + (size_t)r * (4 * T_) + sn + lchunk * 8, &Vt[buf ^ 1][rb * 64]);
            }
        }

        if (s0 <= qrow_base + 31) {
#pragma unroll
            for (int mt = 0; mt < 2; mt++) {
                floatx4 s_acc[4];
#pragma unroll
                for (int nt = 0; nt < 4; nt++) {
                    int krow = nt * 16 + l16;
                    const short8* kb0 = (const short8*)&Ks[buf][krow * 64 + ((quad       ^ (l16 & 7)) * 8)];
                    const short8* kb1 = (const short8*)&Ks[buf][krow * 64 + (((4 + quad) ^ (l16 & 7)) * 8)];
                    floatx4 z = {0.f, 0.f, 0.f, 0.f};
                    z = __builtin_amdgcn_mfma_f32_16x16x32_bf16(qa[mt][0], *kb0, z, 0, 0, 0);
                    s_acc[nt] = __builtin_amdgcn_mfma_f32_16x16x32_bf16(qa[mt][1], *kb1, z, 0, 0, 0);
                }
                int base_mt = qrow_base + mt * 16;
                if (s0 + 63 > base_mt) {
#pragma unroll
                    for (int nt = 0; nt < 4; nt++)
#pragma unroll
                        for (int r = 0; r < 4; r++) {
                            int gi = base_mt + quad * 4 + r;
                            int gj = s0 + nt * 16 + l16;
                            if (gj > gi) s_acc[nt][r] = -INFINITY;
                        }
                }
#pragma unroll
                for (int nt = 0; nt < 4; nt++)
#pragma unroll
                    for (int r = 0; r < 4; r++) {
                        float e = __expf(s_acc[nt][r]);
                        s_acc[nt][r] = e;
                        l_part[mt][r] += e;
                        Ps[wave][(mt * 16 + quad * 4 + r) * 72 + nt * 16 + l16] = f2bf(e);
                    }
            }
            asm volatile("s_waitcnt lgkmcnt(0)" ::: "memory");
            short8 pa[2][2];
#pragma unroll
            for (int mt = 0; mt < 2; mt++) {
                pa[mt][0] = *(const short8*)&Ps[wave][(mt * 16 + l16) * 72 + quad * 8];
                pa[mt][1] = *(const short8*)&Ps[wave][(mt * 16 + l16) * 72 + quad * 8 + 32];
            }
#pragma unroll
            for (int dt = 0; dt < 4; dt++) {
                int vrow = dt * 16 + l16;
                const short8* vb0 = (const short8*)&Vt[buf][vrow * 64 + ((quad       ^ (l16 & 7)) * 8)];
                const short8* vb1 = (const short8*)&Vt[buf][vrow * 64 + (((4 + quad) ^ (l16 & 7)) * 8)];
#pragma unroll
                for (int mt = 0; mt < 2; mt++) {
                    o_acc[mt][dt] = __builtin_amdgcn_mfma_f32_16x16x32_bf16(pa[mt][0], *vb0, o_acc[mt][dt], 0, 0, 0);
                    o_acc[mt][dt] = __builtin_amdgcn_mfma_f32_16x16x32_bf16(pa[mt][1], *vb1, o_acc[mt][dt], 0, 0, 0);
                }
            }
        }
    }

#pragma unroll
    for (int mt = 0; mt < 2; mt++)
#pragma unroll
        for (int r = 0; r < 4; r++) {
            float ls = l_part[mt][r];
            ls += __shfl_xor(ls, 1);
            ls += __shfl_xor(ls, 2);
            ls += __shfl_xor(ls, 4);
            ls += __shfl_xor(ls, 8);
            float inv = 1.f / ls;
            int gi = qrow_base + mt * 16 + quad * 4 + r;
            ushort* op = attnb + (size_t)(b * T_ + gi) * 1024 + h * 64;
#pragma unroll
            for (int dt = 0; dt < 4; dt++)
                op[dt * 16 + l16] = f2bf(o_acc[mt][dt][r] * inv);
        }
}

extern "C" void kernel_launch(void* const* d_in, const int* in_sizes, int n_in,
                              void* d_out, int out_size, void* d_ws, size_t ws_size,
                              hipStream_t stream) {
    (void)in_sizes; (void)n_in; (void)out_size; (void)ws_size;
    const float* x      = (const float*)d_in[0];
    const float* wq     = (const float*)d_in[1];
    const float* wk     = (const float*)d_in[2];
    const float* wv     = (const float*)d_in[3];
    const float* w_proj = (const float*)d_in[4];
    const float* b_proj = (const float*)d_in[5];
    const float* w1     = (const float*)d_in[6];
    const float* b1     = (const float*)d_in[7];
    const float* w2     = (const float*)d_in[8];
    const float* b2     = (const float*)d_in[9];
    const float* g1     = (const float*)d_in[10];
    const float* be1    = (const float*)d_in[11];
    const float* g2     = (const float*)d_in[12];
    const float* be2    = (const float*)d_in[13];
    float* out = (float*)d_out;

    char* ws = (char*)d_ws;
    const size_t MB = 1024ull * 1024ull;
    ushort* xn     = (ushort*)(ws + 0);        // 16 MB (reused as xn2 later)
    ushort* qkv    = (ushort*)(ws + 16 * MB);  // 48 MB
    ushort* attnb  = (ushort*)(ws + 64 * MB);  // 16 MB
    ushort* hbuf   = (ushort*)(ws + 16 * MB);  // 64 MB (aliases qkv+attnb, disjoint lifetime)
    float*  x1     = (float*) (ws + 80 * MB);  // 32 MB (written by proj, after attn)
    ushort* VtG    = (ushort*)(ws + 80 * MB);  // 16 MB (aliases x1; dead once proj runs)
    ushort* WqkvT  = (ushort*)(ws + 112 * MB); // 6 MB
    ushort* WprojT = (ushort*)(ws + 118 * MB); // 2 MB
    ushort* W1T    = (ushort*)(ws + 120 * MB); // 8 MB
    ushort* W2T    = (ushort*)(ws + 128 * MB); // 8 MB
    ushort* xn2 = xn;

    dim3 tb(32, 8);
    ln_kernel<<<M_, 256, 0, stream>>>(x, g1, be1, xn);
    transpose_conv<<<dim3(D_ / 32, C_ / 32, H_), tb, 0, stream>>>(wq, WqkvT,               C_, D_, (long long)C_ * D_, (long long)D_ * C_);
    transpose_conv<<<dim3(D_ / 32, C_ / 32, H_), tb, 0, stream>>>(wk, WqkvT + C_ * C_,     C_, D_, (long long)C_ * D_, (long long)D_ * C_);
    transpose_conv<<<dim3(D_ / 32, C_ / 32, H_), tb, 0, stream>>>(wv, WqkvT + 2 * C_ * C_, C_, D_, (long long)C_ * D_, (long long)D_ * C_);
    transpose_conv<<<dim3(C_ / 32, C_ / 32, 1), tb, 0, stream>>>(w_proj, WprojT, C_, C_, 0, 0);
    transpose_conv<<<dim3(4 * C_ / 32, C_ / 32, 1), tb, 0, stream>>>(w1, W1T, C_, 4 * C_, 0, 0);
    transpose_conv<<<dim3(C_ / 32, 4 * C_ / 32, 1), tb, 0, stream>>>(w2, W2T, 4 * C_, C_, 0, 0);
    // QKV: N=3072, gemm3b control, grid 24x32=768
    gemm3b_kernel<true, false, false, false><<<dim3(3072 / 128, M_ / 256), 512, 0, stream>>>(
        xn, WqkvT, nullptr, nullptr, qkv, M_, 3072, C_);
    vtrans_kernel<<<dim3(T_ / 64, B_ * H_), 256, 0, stream>>>(qkv, VtG);
    attn_kernel<<<1024, 256, 0, stream>>>(qkv, VtG, attnb);
    // proj: N=1024, gemm3b control, grid 8x32=256
    gemm3b_kernel<false, true, false, true><<<dim3(C_ / 128, M_ / 256), 512, 0, stream>>>(
        attnb, WprojT, b_proj, x, x1, M_, C_, C_);
    ln_kernel<<<M_, 256, 0, stream>>>(x1, g2, be2, xn2);
    // FFN1: N=4096, gemm128 superrow-swizzled (3 blocks/CU), grid 32x64=2048
    gemm128_kernel<true, true, true, false><<<dim3(4 * C_ / 128, M_ / 128), 256, 0, stream>>>(
        xn2, W1T, b1, nullptr, hbuf, M_, 4 * C_, C_);
    // FFN2: N=1024, K=4096, gemm128 superrow-swizzled (3 blocks/CU), grid 8x64=512
    gemm128_kernel<false, true, false, true><<<dim3(C_ / 128, M_ / 128), 256, 0, stream>>>(
        hbuf, W2T, b2, x1, out, M_, C_, 4 * C_);
}

// Round 8
// 475.318 us; speedup vs baseline: 1.0503x; 1.0503x over previous
//
#include <hip/hip_runtime.h>
#include <hip/hip_bf16.h>

#define B_ 4
#define T_ 2048
#define C_ 1024
#define H_ 16
#define D_ 64
#define M_ (B_*T_)   // 8192

typedef unsigned short ushort;
typedef __attribute__((ext_vector_type(8))) short short8;
typedef __attribute__((ext_vector_type(8))) unsigned short ushort8;
typedef __attribute__((ext_vector_type(4))) float floatx4;
typedef __attribute__((ext_vector_type(4))) unsigned int uintx4;

static __device__ __forceinline__ float bf2f(ushort u) {
    unsigned int x = ((unsigned int)u) << 16;
    return __builtin_bit_cast(float, x);
}
static __device__ __forceinline__ ushort f2bf(float f) {
    unsigned int x = __builtin_bit_cast(unsigned int, f);
    unsigned int r = (x + 0x7fffu + ((x >> 16) & 1u)) >> 16;
    return (ushort)r;
}

typedef const __attribute__((address_space(1))) unsigned int gu32;
typedef __attribute__((address_space(3))) unsigned int lu32;
static __device__ __forceinline__ void glds16(const void* g, void* l) {
    __builtin_amdgcn_global_load_lds((gu32*)g, (lu32*)l, 16, 0, 0);
}

// ---------------- LayerNorm: fp32 in -> bf16 out ----------------
__global__ __launch_bounds__(256) void ln_kernel(
    const float* __restrict__ x, const float* __restrict__ g,
    const float* __restrict__ be, ushort* __restrict__ out)
{
    int row = blockIdx.x;
    int tid = threadIdx.x;
    const float* xr = x + (size_t)row * C_;
    float v[4];
    float s = 0.f, s2 = 0.f;
#pragma unroll
    for (int i = 0; i < 4; i++) {
        float t = xr[tid + i * 256];
        v[i] = t; s += t; s2 += t * t;
    }
#pragma unroll
    for (int off = 32; off; off >>= 1) {
        s  += __shfl_down(s, off);
        s2 += __shfl_down(s2, off);
    }
    __shared__ float rs[4], rs2[4];
    __shared__ float smu, srstd;
    int w = tid >> 6;
    if ((tid & 63) == 0) { rs[w] = s; rs2[w] = s2; }
    __syncthreads();
    if (tid == 0) {
        float ts  = rs[0] + rs[1] + rs[2] + rs[3];
        float ts2 = rs2[0] + rs2[1] + rs2[2] + rs2[3];
        float mu  = ts * (1.f / C_);
        float var = ts2 * (1.f / C_) - mu * mu;
        smu = mu; srstd = rsqrtf(var + 1e-5f);
    }
    __syncthreads();
    float mu = smu, r = srstd;
#pragma unroll
    for (int i = 0; i < 4; i++) {
        int c = tid + i * 256;
        out[(size_t)row * C_ + c] = f2bf((v[i] - mu) * r * g[c] + be[c]);
    }
}

// ------------- transpose + fp32->bf16 convert: in (R x Cn) -> out (Cn x R) -------------
__global__ __launch_bounds__(256) void transpose_conv(
    const float* __restrict__ in, ushort* __restrict__ out,
    int R, int Cn, long long in_bstride, long long out_bstride)
{
    __shared__ float tile[32][33];
    const float* ip = in + (size_t)blockIdx.z * in_bstride;
    ushort* op = out + (size_t)blockIdx.z * out_bstride;
    int tx = threadIdx.x;          // 32
    int ty = threadIdx.y;          // 8
    int c0 = blockIdx.x * 32, r0 = blockIdx.y * 32;
#pragma unroll
    for (int i = 0; i < 32; i += 8) {
        tile[ty + i][tx] = ip[(size_t)(r0 + ty + i) * Cn + c0 + tx];
    }
    __syncthreads();
#pragma unroll
    for (int i = 0; i < 32; i += 8) {
        int oc = c0 + ty + i;
        int orr = r0 + tx;
        op[(size_t)oc * R + orr] = f2bf(tile[tx][ty + i]);
    }
}

// ------------- V transpose: qkv V block -> VtG[(h*256 + 4*d + b)*2048 + t] -------------
__global__ __launch_bounds__(256) void vtrans_kernel(
    const ushort* __restrict__ qkv, ushort* __restrict__ VtG)
{
    int bh = blockIdx.y;
    int b = bh >> 4, h = bh & 15;
    int j0 = blockIdx.x * 64;
    int tid = threadIdx.x;
    __shared__ unsigned int X[64 * 33];
    const ushort* Vg = qkv + (size_t)(b * T_) * 3072 + 2048 + h * 64;
#pragma unroll
    for (int it = 0; it < 2; it++) {
        int j = (tid >> 3) + it * 32;
        int dp = (tid & 7) * 4;
        uintx4 val = *(const uintx4*)(Vg + (size_t)(j0 + j) * 3072 + dp * 2);
#pragma unroll
        for (int k = 0; k < 4; k++) X[j * 33 + dp + k] = val[k];
    }
    __syncthreads();
    int dp = tid >> 3, jc = tid & 7;
    unsigned int v[8];
#pragma unroll
    for (int jj = 0; jj < 8; jj++) v[jj] = X[(jc * 8 + jj) * 33 + dp];
    ushort8 lo, hi;
#pragma unroll
    for (int jj = 0; jj < 8; jj++) {
        lo[jj] = (ushort)(v[jj] & 0xffffu);
        hi[jj] = (ushort)(v[jj] >> 16);
    }
    size_t r0 = ((size_t)(h * 256 + 4 * (2 * dp) + b)) * T_ + j0 + jc * 8;
    size_t r1 = ((size_t)(h * 256 + 4 * (2 * dp + 1) + b)) * T_ + j0 + jc * 8;
    *(ushort8*)&VtG[r0] = lo;
    *(ushort8*)&VtG[r1] = hi;
}

// ================= Corrected 8-phase 256x256 GEMM (m201 ledger-derived) =================
// BM=BN=256, BK=64, 8 waves (wr=wave>>2, wc=wave&3), per-wave C 128x64 (rows q*64+wr*32+{0,16}).
// LDS 128 KiB: AL/BL[2buf][2half][128x64]. Per K-tile 4 phases: {reads (12 at ph0, else 4) |
// stage dead-slot halves} -> bar -> lgkm0 -> schedbar -> 16 MFMA -> bar.
// Slot deaths: B halves after ph0; A-h0 after ph1; A-h1 after ph3 -> stage schedule per iter j
// (ta=2j buf0, tb=2j+1 buf1): ph0:A1h0<-tb; ph1:A1h1<-tb,B0h0<-ta+2; ph2:B0h1<-ta+2;
// ph4:A0h0<-ta+2; ph5:A0h1<-ta+2; ph6:B1h0<-tb+2; ph7:B1h1<-tb+2.
// vmcnt(4) ONLY at ends of ph3 (buf1 resident) and ph7 (buf0-next resident) - 4 newer loads
// stay in flight. Tail stages clamp tile index (re-stage, never read) so counts stay uniform.
template<bool OUTBF16, bool BIAS, bool RELU, bool RESID>
__global__ __launch_bounds__(512, 2) void gemm8p_kernel(
    const ushort* __restrict__ A,
    const ushort* __restrict__ Bt,
    const float* __restrict__ bias,
    const float* __restrict__ resid,
    void* __restrict__ Cout,
    int Mdim, int Ndim, int K)
{
    __shared__ ushort AL[2][2][128 * 64];
    __shared__ ushort BL[2][2][128 * 64];

    int gridX = gridDim.x;
    int nwg = gridX * gridDim.y;
    int bid = blockIdx.y * gridX + blockIdx.x;
    int cpx = nwg >> 3;
    int swz = (bid & 7) * cpx + (bid >> 3);
    int bx = swz % gridX, by = swz / gridX;
    int m0 = by * 256, n0 = bx * 256;

    int tid = threadIdx.x;
    int wave = tid >> 6, lane = tid & 63;
    int quad = lane >> 4, l16 = lane & 15;
    int wr = wave >> 2, wc = wave & 3;
    int lrow = lane >> 3;
    int lchunk = (lane & 7) ^ (lrow & 7);

    int nt = K >> 6;                        // even at all call sites

    auto stA = [&](int t, int b, int h) {
        if (t >= nt) t = nt - 1;            // tail clamp
#pragma unroll
        for (int it = 0; it < 2; it++) {
            int rb = it * 64 + wave * 8;
            glds16(A + (size_t)(m0 + h * 128 + rb + lrow) * K + (t << 6) + lchunk * 8,
                   &AL[b][h][rb * 64]);
        }
    };
    auto stB = [&](int t, int b, int h) {
        if (t >= nt) t = nt - 1;
#pragma unroll
        for (int it = 0; it < 2; it++) {
            int rb = it * 64 + wave * 8;
            glds16(Bt + (size_t)(n0 + h * 128 + rb + lrow) * K + (t << 6) + lchunk * 8,
                   &BL[b][h][rb * 64]);
        }
    };

    floatx4 acc[8][4] = {};
    short8 Bf[4][2];
    short8 Af[2][2];

    auto rdB = [&](int b) {
#pragma unroll
        for (int n = 0; n < 4; n++) {
            int nr = wc * 64 + n * 16 + l16;
            int h = nr >> 7, r = nr & 127;
#pragma unroll
            for (int kk = 0; kk < 2; kk++)
                Bf[n][kk] = *(const short8*)&BL[b][h][r * 64 + (((kk * 4 + quad) ^ (r & 7)) * 8)];
        }
    };
    auto rdA = [&](int b, int q) {
#pragma unroll
        for (int mi = 0; mi < 2; mi++) {
            int R = q * 64 + wr * 32 + mi * 16 + l16;
            int h = R >> 7, r = R & 127;
#pragma unroll
            for (int kk = 0; kk < 2; kk++)
                Af[mi][kk] = *(const short8*)&AL[b][h][r * 64 + (((kk * 4 + quad) ^ (r & 7)) * 8)];
        }
    };
    auto mmq = [&](int q) {
        __builtin_amdgcn_s_setprio(1);
#pragma unroll
        for (int kk = 0; kk < 2; kk++)
#pragma unroll
            for (int mi = 0; mi < 2; mi++)
#pragma unroll
                for (int n = 0; n < 4; n++)
                    acc[q * 2 + mi][n] = __builtin_amdgcn_mfma_f32_16x16x32_bf16(
                        Af[mi][kk], Bf[n][kk], acc[q * 2 + mi][n], 0, 0, 0);
        __builtin_amdgcn_s_setprio(0);
    };

#define BAR()   __builtin_amdgcn_s_barrier()
#define LGKM0() asm volatile("s_waitcnt lgkmcnt(0)" ::: "memory")
#define SCHB()  __builtin_amdgcn_sched_barrier(0)
#define VM4()   asm volatile("s_waitcnt vmcnt(4)" ::: "memory")

    // Prologue: 12 loads establishing the steady-state invariant; vmcnt(4) -> tile0 resident,
    // B1 halves (4 loads) stay in flight (matches steady state at iteration entry).
    stB(0, 0, 0); stB(0, 0, 1); stA(0, 0, 0); stA(0, 0, 1);
    stB(1, 1, 0); stB(1, 1, 1);
    VM4();
    BAR();

    int J = nt >> 1;
    for (int j = 0; j < J; j++) {
        int ta = 2 * j, tb = 2 * j + 1;
        // ---- tile ta (buf0) ----
        rdB(0); rdA(0, 0);  stA(tb, 1, 0);
        BAR(); LGKM0(); SCHB(); mmq(0); BAR();
        rdA(0, 1);          stA(tb, 1, 1); stB(ta + 2, 0, 0);
        BAR(); LGKM0(); SCHB(); mmq(1); BAR();
        rdA(0, 2);          stB(ta + 2, 0, 1);
        BAR(); LGKM0(); SCHB(); mmq(2); BAR();
        rdA(0, 3);
        BAR(); LGKM0(); SCHB(); mmq(3);
        VM4();  // buf1 (tb) fully resident; ta+2's B halves stay in flight
        BAR();
        // ---- tile tb (buf1) ----
        rdB(1); rdA(1, 0);  stA(ta + 2, 0, 0);
        BAR(); LGKM0(); SCHB(); mmq(0); BAR();
        rdA(1, 1);          stA(ta + 2, 0, 1);
        BAR(); LGKM0(); SCHB(); mmq(1); BAR();
        rdA(1, 2);          stB(tb + 2, 1, 0);
        BAR(); LGKM0(); SCHB(); mmq(2); BAR();
        rdA(1, 3);          stB(tb + 2, 1, 1);
        BAR(); LGKM0(); SCHB(); mmq(3);
        VM4();  // buf0 (ta+2) fully resident; tb+2's B halves stay in flight
        BAR();
    }
#undef BAR
#undef LGKM0
#undef SCHB
#undef VM4

    // epilogue
#pragma unroll
    for (int am = 0; am < 8; am++) {
        int q = am >> 1, mi = am & 1;
#pragma unroll
        for (int n = 0; n < 4; n++) {
#pragma unroll
            for (int r = 0; r < 4; r++) {
                int gm = m0 + q * 64 + wr * 32 + mi * 16 + quad * 4 + r;
                int gn = n0 + wc * 64 + n * 16 + l16;
                float v = acc[am][n][r];
                if (BIAS)  v += bias[gn];
                if (RESID) v += resid[(size_t)gm * Ndim + gn];
                if (RELU)  v = fmaxf(v, 0.f);
                if (OUTBF16) ((ushort*)Cout)[(size_t)gm * Ndim + gn] = f2bf(v);
                else         ((float*)Cout)[(size_t)gm * Ndim + gn] = v;
            }
        }
    }
}

// ============ 3-buffer rotating bf16 MFMA GEMM (R5-proven): BM=256, BN=128, BK=64 ============
template<bool OUTBF16, bool BIAS, bool RELU, bool RESID>
__global__ __launch_bounds__(512, 2) void gemm3b_kernel(
    const ushort* __restrict__ A,
    const ushort* __restrict__ Bt,
    const float* __restrict__ bias,
    const float* __restrict__ resid,
    void* __restrict__ Cout,
    int Mdim, int Ndim, int K)
{
    __shared__ ushort As[3][256 * 64];
    __shared__ ushort Bs[3][128 * 64];

    int gridX = gridDim.x;
    int nwg = gridX * gridDim.y;
    int bid = blockIdx.y * gridX + blockIdx.x;
    int cpx = nwg >> 3;
    int swz = (bid & 7) * cpx + (bid >> 3);
    int bx = swz % gridX, by = swz / gridX;
    int m0 = by * 256, n0 = bx * 128;

    int tid = threadIdx.x;
    int wave = tid >> 6, lane = tid & 63;
    int quad = lane >> 4, l16 = lane & 15;
    int wr = wave >> 1, wc = wave & 1;
    int wm = wr * 64, wn = wc * 64;
    int lrow = lane >> 3;
    int lchunk = (lane & 7) ^ (lrow & 7);

    floatx4 acc[4][4] = {};
    int nt = K >> 6;

    auto stage = [&](int t, int sb) {
        int k0 = t << 6;
#pragma unroll
        for (int it = 0; it < 4; it++) {
            int rb = it * 64 + wave * 8;
            glds16(A + (size_t)(m0 + rb + lrow) * K + k0 + lchunk * 8, &As[sb][rb * 64]);
        }
#pragma unroll
        for (int it = 0; it < 2; it++) {
            int rb = it * 64 + wave * 8;
            glds16(Bt + (size_t)(n0 + rb + lrow) * K + k0 + lchunk * 8, &Bs[sb][rb * 64]);
        }
    };

    stage(0, 0);
    stage(1, 1);
    asm volatile("s_waitcnt vmcnt(6)" ::: "memory");
    __builtin_amdgcn_s_barrier();
    asm volatile("" ::: "memory");

    int s0 = 0, s1 = 1, s2 = 2;
    for (int t = 0; t < nt; ++t) {
        short8 af[4][2], bfv[4][2];
#pragma unroll
        for (int kk = 0; kk < 2; kk++) {
            int c = kk * 4 + quad;
#pragma unroll
            for (int mi = 0; mi < 4; mi++) {
                int r = wm + mi * 16 + l16;
                af[mi][kk] = *(const short8*)&As[s0][r * 64 + ((c ^ (r & 7)) * 8)];
            }
#pragma unroll
            for (int ni = 0; ni < 4; ni++) {
                int r = wn + ni * 16 + l16;
                bfv[ni][kk] = *(const short8*)&Bs[s0][r * 64 + ((c ^ (r & 7)) * 8)];
            }
        }
        bool pf = (t + 2 < nt);
        if (pf) stage(t + 2, s2);
        __builtin_amdgcn_s_setprio(1);
#pragma unroll
        for (int kk = 0; kk < 2; kk++)
#pragma unroll
            for (int mi = 0; mi < 4; mi++)
#pragma unroll
                for (int ni = 0; ni < 4; ni++)
                    acc[mi][ni] = __builtin_amdgcn_mfma_f32_16x16x32_bf16(
                        af[mi][kk], bfv[ni][kk], acc[mi][ni], 0, 0, 0);
        __builtin_amdgcn_s_setprio(0);
        if (pf) asm volatile("s_waitcnt vmcnt(6)" ::: "memory");
        else    asm volatile("s_waitcnt vmcnt(0)" ::: "memory");
        __builtin_amdgcn_s_barrier();
        asm volatile("" ::: "memory");
        int tmp = s0; s0 = s1; s1 = s2; s2 = tmp;
    }

    int r4 = quad * 4;
#pragma unroll
    for (int mi = 0; mi < 4; mi++) {
#pragma unroll
        for (int ni = 0; ni < 4; ni++) {
#pragma unroll
            for (int r = 0; r < 4; r++) {
                int gm = m0 + wm + mi * 16 + r4 + r;
                int gn = n0 + wn + ni * 16 + l16;
                float v = acc[mi][ni][r];
                if (BIAS)  v += bias[gn];
                if (RESID) v += resid[(size_t)gm * Ndim + gn];
                if (RELU)  v = fmaxf(v, 0.f);
                if (OUTBF16) ((ushort*)Cout)[(size_t)gm * Ndim + gn] = f2bf(v);
                else         ((float*)Cout)[(size_t)gm * Ndim + gn] = v;
            }
        }
    }
}

// ---------------- causal flash attention: XCD-swizzled, dbuf glds, static-max softmax ----------------
__global__ __launch_bounds__(256, 2) void attn_kernel(
    const ushort* __restrict__ qkv,
    const ushort* __restrict__ VtG,   // (h*256 + 4*d + b)*2048 + t
    ushort* __restrict__ attnb)
{
    const int LD = 3072;
    int bid = blockIdx.x;
    int bh = (bid & 7) * 8 + ((bid >> 3) & 7);
    int qt = 15 - (bid >> 6);
    int b = bh >> 4, h = bh & 15;
    int t0 = qt * 128;
    int tid = threadIdx.x;
    int wave = tid >> 6, lane = tid & 63;
    int quad = lane >> 4, l16 = lane & 15;

    __shared__ ushort Ks[2][64 * 64];
    __shared__ ushort Vt[2][64 * 64];
    __shared__ ushort Ps[4][32 * 72];

    const ushort* Qg = qkv + (size_t)(b * T_) * LD + h * 64;
    const ushort* Kg = Qg + 1024;
    const ushort* VtB = VtG + (size_t)(h * 256 + b) * T_;

    int qrow_base = t0 + wave * 32;
    int lrow = lane >> 3;
    int lchunk = (lane & 7) ^ (lrow & 7);

    short8 qa[2][2];
#pragma unroll
    for (int mt = 0; mt < 2; mt++) {
        const ushort* qp = Qg + (size_t)(qrow_base + mt * 16 + l16) * LD + quad * 8;
        ushort8 q0 = *(const ushort8*)qp;
        ushort8 q1 = *(const ushort8*)(qp + 32);
        ushort8 a0, a1;
#pragma unroll
        for (int d = 0; d < 8; d++) {
            a0[d] = f2bf(bf2f(q0[d]) * 0.03125f);
            a1[d] = f2bf(bf2f(q1[d]) * 0.03125f);
        }
        qa[mt][0] = __builtin_bit_cast(short8, a0);
        qa[mt][1] = __builtin_bit_cast(short8, a1);
    }

    float l_part[2][4];
    floatx4 o_acc[2][4];
#pragma unroll
    for (int mt = 0; mt < 2; mt++)
#pragma unroll
        for (int r = 0; r < 4; r++) {
            l_part[mt][r] = 0.f;
            o_acc[mt][r] = floatx4{0.f, 0.f, 0.f, 0.f};
        }

    int nIter = t0 / 64 + 2;

#pragma unroll
    for (int it = 0; it < 2; it++) {
        int rb = (wave * 2 + it) * 8;
        int r = rb + lrow;
        glds16(Kg  + (size_t)r * LD + lchunk * 8, &Ks[0][rb * 64]);
        glds16(VtB + (size_t)r * (4 * T_) + lchunk * 8, &Vt[0][rb * 64]);
    }

    for (int ii = 0; ii < nIter; ii++) {
        int s0 = ii * 64;
        int buf = ii & 1;
        __syncthreads();
        if (ii + 1 < nIter) {
            int sn = s0 + 64;
#pragma unroll
            for (int it = 0; it < 2; it++) {
                int rb = (wave * 2 + it) * 8;
                int r = rb + lrow;
                glds16(Kg  + (size_t)(sn + r) * LD + lchunk * 8, &Ks[buf ^ 1][rb * 64]);
                glds16(VtB + (size_t)r * (4 * T_) + sn + lchunk * 8, &Vt[buf ^ 1][rb * 64]);
            }
        }

        if (s0 <= qrow_base + 31) {
#pragma unroll
            for (int mt = 0; mt < 2; mt++) {
                floatx4 s_acc[4];
#pragma unroll
                for (int nt = 0; nt < 4; nt++) {
                    int krow = nt * 16 + l16;
                    const short8* kb0 = (const short8*)&Ks[buf][krow * 64 + ((quad       ^ (l16 & 7)) * 8)];
                    const short8* kb1 = (const short8*)&Ks[buf][krow * 64 + (((4 + quad) ^ (l16 & 7)) * 8)];
                    floatx4 z = {0.f, 0.f, 0.f, 0.f};
                    z = __builtin_amdgcn_mfma_f32_16x16x32_bf16(qa[mt][0], *kb0, z, 0, 0, 0);
                    s_acc[nt] = __builtin_amdgcn_mfma_f32_16x16x32_bf16(qa[mt][1], *kb1, z, 0, 0, 0);
                }
                int base_mt = qrow_base + mt * 16;
                if (s0 + 63 > base_mt) {
#pragma unroll
                    for (int nt = 0; nt < 4; nt++)
#pragma unroll
                        for (int r = 0; r < 4; r++) {
                            int gi = base_mt + quad * 4 + r;
                            int gj = s0 + nt * 16 + l16;
                            if (gj > gi) s_acc[nt][r] = -INFINITY;
                        }
                }
#pragma unroll
                for (int nt = 0; nt < 4; nt++)
#pragma unroll
                    for (int r = 0; r < 4; r++) {
                        float e = __expf(s_acc[nt][r]);
                        s_acc[nt][r] = e;
                        l_part[mt][r] += e;
                        Ps[wave][(mt * 16 + quad * 4 + r) * 72 + nt * 16 + l16] = f2bf(e);
                    }
            }
            asm volatile("s_waitcnt lgkmcnt(0)" ::: "memory");
            short8 pa[2][2];
#pragma unroll
            for (int mt = 0; mt < 2; mt++) {
                pa[mt][0] = *(const short8*)&Ps[wave][(mt * 16 + l16) * 72 + quad * 8];
                pa[mt][1] = *(const short8*)&Ps[wave][(mt * 16 + l16) * 72 + quad * 8 + 32];
            }
#pragma unroll
            for (int dt = 0; dt < 4; dt++) {
                int vrow = dt * 16 + l16;
                const short8* vb0 = (const short8*)&Vt[buf][vrow * 64 + ((quad       ^ (l16 & 7)) * 8)];
                const short8* vb1 = (const short8*)&Vt[buf][vrow * 64 + (((4 + quad) ^ (l16 & 7)) * 8)];
#pragma unroll
                for (int mt = 0; mt < 2; mt++) {
                    o_acc[mt][dt] = __builtin_amdgcn_mfma_f32_16x16x32_bf16(pa[mt][0], *vb0, o_acc[mt][dt], 0, 0, 0);
                    o_acc[mt][dt] = __builtin_amdgcn_mfma_f32_16x16x32_bf16(pa[mt][1], *vb1, o_acc[mt][dt], 0, 0, 0);
                }
            }
        }
    }

#pragma unroll
    for (int mt = 0; mt < 2; mt++)
#pragma unroll
        for (int r = 0; r < 4; r++) {
            float ls = l_part[mt][r];
            ls += __shfl_xor(ls, 1);
            ls += __shfl_xor(ls, 2);
            ls += __shfl_xor(ls, 4);
            ls += __shfl_xor(ls, 8);
            float inv = 1.f / ls;
            int gi = qrow_base + mt * 16 + quad * 4 + r;
            ushort* op = attnb + (size_t)(b * T_ + gi) * 1024 + h * 64;
#pragma unroll
            for (int dt = 0; dt < 4; dt++)
                op[dt * 16 + l16] = f2bf(o_acc[mt][dt][r] * inv);
        }
}

extern "C" void kernel_launch(void* const* d_in, const int* in_sizes, int n_in,
                              void* d_out, int out_size, void* d_ws, size_t ws_size,
                              hipStream_t stream) {
    (void)in_sizes; (void)n_in; (void)out_size; (void)ws_size;
    const float* x      = (const float*)d_in[0];
    const float* wq     = (const float*)d_in[1];
    const float* wk     = (const float*)d_in[2];
    const float* wv     = (const float*)d_in[3];
    const float* w_proj = (const float*)d_in[4];
    const float* b_proj = (const float*)d_in[5];
    const float* w1     = (const float*)d_in[6];
    const float* b1     = (const float*)d_in[7];
    const float* w2     = (const float*)d_in[8];
    const float* b2     = (const float*)d_in[9];
    const float* g1     = (const float*)d_in[10];
    const float* be1    = (const float*)d_in[11];
    const float* g2     = (const float*)d_in[12];
    const float* be2    = (const float*)d_in[13];
    float* out = (float*)d_out;

    char* ws = (char*)d_ws;
    const size_t MB = 1024ull * 1024ull;
    ushort* xn     = (ushort*)(ws + 0);        // 16 MB (reused as xn2 later)
    ushort* qkv    = (ushort*)(ws + 16 * MB);  // 48 MB
    ushort* attnb  = (ushort*)(ws + 64 * MB);  // 16 MB
    ushort* hbuf   = (ushort*)(ws + 16 * MB);  // 64 MB (aliases qkv+attnb, disjoint lifetime)
    float*  x1     = (float*) (ws + 80 * MB);  // 32 MB (written by proj, after attn)
    ushort* VtG    = (ushort*)(ws + 80 * MB);  // 16 MB (aliases x1; dead once proj runs)
    ushort* WqkvT  = (ushort*)(ws + 112 * MB); // 6 MB
    ushort* WprojT = (ushort*)(ws + 118 * MB); // 2 MB
    ushort* W1T    = (ushort*)(ws + 120 * MB); // 8 MB
    ushort* W2T    = (ushort*)(ws + 128 * MB); // 8 MB
    ushort* xn2 = xn;

    dim3 tb(32, 8);
    ln_kernel<<<M_, 256, 0, stream>>>(x, g1, be1, xn);
    transpose_conv<<<dim3(D_ / 32, C_ / 32, H_), tb, 0, stream>>>(wq, WqkvT,               C_, D_, (long long)C_ * D_, (long long)D_ * C_);
    transpose_conv<<<dim3(D_ / 32, C_ / 32, H_), tb, 0, stream>>>(wk, WqkvT + C_ * C_,     C_, D_, (long long)C_ * D_, (long long)D_ * C_);
    transpose_conv<<<dim3(D_ / 32, C_ / 32, H_), tb, 0, stream>>>(wv, WqkvT + 2 * C_ * C_, C_, D_, (long long)C_ * D_, (long long)D_ * C_);
    transpose_conv<<<dim3(C_ / 32, C_ / 32, 1), tb, 0, stream>>>(w_proj, WprojT, C_, C_, 0, 0);
    transpose_conv<<<dim3(4 * C_ / 32, C_ / 32, 1), tb, 0, stream>>>(w1, W1T, C_, 4 * C_, 0, 0);
    transpose_conv<<<dim3(C_ / 32, 4 * C_ / 32, 1), tb, 0, stream>>>(w2, W2T, 4 * C_, C_, 0, 0);
    // QKV: N=3072, gemm3b (R5-proven), grid 24x32=768
    gemm3b_kernel<true, false, false, false><<<dim3(3072 / 128, M_ / 256), 512, 0, stream>>>(
        xn, WqkvT, nullptr, nullptr, qkv, M_, 3072, C_);
    vtrans_kernel<<<dim3(T_ / 64, B_ * H_), 256, 0, stream>>>(qkv, VtG);
    attn_kernel<<<1024, 256, 0, stream>>>(qkv, VtG, attnb);
    // proj: N=1024, gemm3b, grid 8x32=256
    gemm3b_kernel<false, true, false, true><<<dim3(C_ / 128, M_ / 256), 512, 0, stream>>>(
        attnb, WprojT, b_proj, x, x1, M_, C_, C_);
    ln_kernel<<<M_, 256, 0, stream>>>(x1, g2, be2, xn2);
    // FFN1: N=4096, corrected 8-phase 256^2, grid 16x32=512  [A/B vs gemm3b-FFN2 same run]
    gemm8p_kernel<true, true, true, false><<<dim3(4 * C_ / 256, M_ / 256), 512, 0, stream>>>(
        xn2, W1T, b1, nullptr, hbuf, M_, 4 * C_, C_);
    // FFN2: N=1024, K=4096, gemm3b, grid 8x32=256
    gemm3b_kernel<false, true, false, true><<<dim3(C_ / 128, M_ / 256), 512, 0, stream>>>(
        hbuf, W2T, b2, x1, out, M_, C_, 4 * C_);
}

// Round 9
// 436.067 us; speedup vs baseline: 1.1449x; 1.0900x over previous
//
#include <hip/hip_runtime.h>
#include <hip/hip_bf16.h>

#define B_ 4
#define T_ 2048
#define C_ 1024
#define H_ 16
#define D_ 64
#define M_ (B_*T_)   // 8192

typedef unsigned short ushort;
typedef __attribute__((ext_vector_type(8))) short short8;
typedef __attribute__((ext_vector_type(8))) unsigned short ushort8;
typedef __attribute__((ext_vector_type(4))) float floatx4;
typedef __attribute__((ext_vector_type(4))) unsigned int uintx4;

static __device__ __forceinline__ float bf2f(ushort u) {
    unsigned int x = ((unsigned int)u) << 16;
    return __builtin_bit_cast(float, x);
}
static __device__ __forceinline__ ushort f2bf(float f) {
    unsigned int x = __builtin_bit_cast(unsigned int, f);
    unsigned int r = (x + 0x7fffu + ((x >> 16) & 1u)) >> 16;
    return (ushort)r;
}

typedef const __attribute__((address_space(1))) unsigned int gu32;
typedef __attribute__((address_space(3))) unsigned int lu32;
static __device__ __forceinline__ void glds16(const void* g, void* l) {
    __builtin_amdgcn_global_load_lds((gu32*)g, (lu32*)l, 16, 0, 0);
}

// ---------------- LayerNorm: fp32 in -> bf16 out ----------------
__global__ __launch_bounds__(256) void ln_kernel(
    const float* __restrict__ x, const float* __restrict__ g,
    const float* __restrict__ be, ushort* __restrict__ out)
{
    int row = blockIdx.x;
    int tid = threadIdx.x;
    const float* xr = x + (size_t)row * C_;
    float v[4];
    float s = 0.f, s2 = 0.f;
#pragma unroll
    for (int i = 0; i < 4; i++) {
        float t = xr[tid + i * 256];
        v[i] = t; s += t; s2 += t * t;
    }
#pragma unroll
    for (int off = 32; off; off >>= 1) {
        s  += __shfl_down(s, off);
        s2 += __shfl_down(s2, off);
    }
    __shared__ float rs[4], rs2[4];
    __shared__ float smu, srstd;
    int w = tid >> 6;
    if ((tid & 63) == 0) { rs[w] = s; rs2[w] = s2; }
    __syncthreads();
    if (tid == 0) {
        float ts  = rs[0] + rs[1] + rs[2] + rs[3];
        float ts2 = rs2[0] + rs2[1] + rs2[2] + rs2[3];
        float mu  = ts * (1.f / C_);
        float var = ts2 * (1.f / C_) - mu * mu;
        smu = mu; srstd = rsqrtf(var + 1e-5f);
    }
    __syncthreads();
    float mu = smu, r = srstd;
#pragma unroll
    for (int i = 0; i < 4; i++) {
        int c = tid + i * 256;
        out[(size_t)row * C_ + c] = f2bf((v[i] - mu) * r * g[c] + be[c]);
    }
}

// ------- merged weight transpose+convert: ALL 6 weight matrices in ONE launch -------
// blockIdx.x ranges route jobs (block-uniform): [0,3072) wq/wk/wv (per-head),
// [3072,4096) w_proj, [4096,8192) w1, [8192,12288) w2. Each tile: 32x32 via LDS.
__global__ __launch_bounds__(256) void transpose_all(
    const float* __restrict__ wq, const float* __restrict__ wk,
    const float* __restrict__ wv, const float* __restrict__ w_proj,
    const float* __restrict__ w1, const float* __restrict__ w2,
    ushort* __restrict__ WqkvT, ushort* __restrict__ WprojT,
    ushort* __restrict__ W1T, ushort* __restrict__ W2T)
{
    __shared__ float tile[32][33];
    int bidx = blockIdx.x;
    const float* in; ushort* out;
    int R, Cn, c0, r0;
    if (bidx < 3072) {
        int which = bidx >> 10;          // 0=wq 1=wk 2=wv
        int lt = bidx & 1023;
        int z = lt >> 6;                  // head
        int rem = lt & 63;                // 2 x 32 tiles per head
        c0 = (rem & 1) * 32; r0 = (rem >> 1) * 32;
        in = (which == 0 ? wq : which == 1 ? wk : wv) + (size_t)z * C_ * D_;
        out = WqkvT + (size_t)which * C_ * C_ + (size_t)z * D_ * C_;
        R = C_; Cn = D_;
    } else if (bidx < 4096) {
        int lt = bidx - 3072;
        c0 = (lt & 31) * 32; r0 = (lt >> 5) * 32;
        in = w_proj; out = WprojT; R = C_; Cn = C_;
    } else if (bidx < 8192) {
        int lt = bidx - 4096;
        c0 = (lt & 127) * 32; r0 = (lt >> 7) * 32;
        in = w1; out = W1T; R = C_; Cn = 4 * C_;
    } else {
        int lt = bidx - 8192;
        c0 = (lt & 31) * 32; r0 = (lt >> 5) * 32;
        in = w2; out = W2T; R = 4 * C_; Cn = C_;
    }
    int tx = threadIdx.x & 31;
    int ty = threadIdx.x >> 5;
#pragma unroll
    for (int i = 0; i < 32; i += 8) {
        tile[ty + i][tx] = in[(size_t)(r0 + ty + i) * Cn + c0 + tx];
    }
    __syncthreads();
#pragma unroll
    for (int i = 0; i < 32; i += 8) {
        int oc = c0 + ty + i;
        int orr = r0 + tx;
        out[(size_t)oc * R + orr] = f2bf(tile[tx][ty + i]);
    }
}

// ------------- V transpose: qkv V block -> VtG[(h*256 + 4*d + b)*2048 + t] -------------
__global__ __launch_bounds__(256) void vtrans_kernel(
    const ushort* __restrict__ qkv, ushort* __restrict__ VtG)
{
    int bh = blockIdx.y;
    int b = bh >> 4, h = bh & 15;
    int j0 = blockIdx.x * 64;
    int tid = threadIdx.x;
    __shared__ unsigned int X[64 * 33];
    const ushort* Vg = qkv + (size_t)(b * T_) * 3072 + 2048 + h * 64;
#pragma unroll
    for (int it = 0; it < 2; it++) {
        int j = (tid >> 3) + it * 32;
        int dp = (tid & 7) * 4;
        uintx4 val = *(const uintx4*)(Vg + (size_t)(j0 + j) * 3072 + dp * 2);
#pragma unroll
        for (int k = 0; k < 4; k++) X[j * 33 + dp + k] = val[k];
    }
    __syncthreads();
    int dp = tid >> 3, jc = tid & 7;
    unsigned int v[8];
#pragma unroll
    for (int jj = 0; jj < 8; jj++) v[jj] = X[(jc * 8 + jj) * 33 + dp];
    ushort8 lo, hi;
#pragma unroll
    for (int jj = 0; jj < 8; jj++) {
        lo[jj] = (ushort)(v[jj] & 0xffffu);
        hi[jj] = (ushort)(v[jj] >> 16);
    }
    size_t r0 = ((size_t)(h * 256 + 4 * (2 * dp) + b)) * T_ + j0 + jc * 8;
    size_t r1 = ((size_t)(h * 256 + 4 * (2 * dp + 1) + b)) * T_ + j0 + jc * 8;
    *(ushort8*)&VtG[r0] = lo;
    *(ushort8*)&VtG[r1] = hi;
}

// ============ 3-buffer rotating bf16 MFMA GEMM (R5-proven): BM=256, BN=128, BK=64 ============
// Tile t reads slot s0; stage(t+2) -> slot s2 (freed end of t-1, no drain needed);
// ONE counted vmcnt(6) + ONE barrier per K-tile. T1 XCD swizzle + T2 XOR swizzle + T5 setprio.
template<bool OUTBF16, bool BIAS, bool RELU, bool RESID>
__global__ __launch_bounds__(512, 2) void gemm3b_kernel(
    const ushort* __restrict__ A,
    const ushort* __restrict__ Bt,
    const float* __restrict__ bias,
    const float* __restrict__ resid,
    void* __restrict__ Cout,
    int Mdim, int Ndim, int K)
{
    __shared__ ushort As[3][256 * 64];
    __shared__ ushort Bs[3][128 * 64];

    int gridX = gridDim.x;
    int nwg = gridX * gridDim.y;
    int bid = blockIdx.y * gridX + blockIdx.x;
    int cpx = nwg >> 3;
    int swz = (bid & 7) * cpx + (bid >> 3);
    int bx = swz % gridX, by = swz / gridX;
    int m0 = by * 256, n0 = bx * 128;

    int tid = threadIdx.x;
    int wave = tid >> 6, lane = tid & 63;
    int quad = lane >> 4, l16 = lane & 15;
    int wr = wave >> 1, wc = wave & 1;
    int wm = wr * 64, wn = wc * 64;
    int lrow = lane >> 3;
    int lchunk = (lane & 7) ^ (lrow & 7);

    floatx4 acc[4][4] = {};
    int nt = K >> 6;

    auto stage = [&](int t, int sb) {
        int k0 = t << 6;
#pragma unroll
        for (int it = 0; it < 4; it++) {
            int rb = it * 64 + wave * 8;
            glds16(A + (size_t)(m0 + rb + lrow) * K + k0 + lchunk * 8, &As[sb][rb * 64]);
        }
#pragma unroll
        for (int it = 0; it < 2; it++) {
            int rb = it * 64 + wave * 8;
            glds16(Bt + (size_t)(n0 + rb + lrow) * K + k0 + lchunk * 8, &Bs[sb][rb * 64]);
        }
    };

    stage(0, 0);
    stage(1, 1);
    asm volatile("s_waitcnt vmcnt(6)" ::: "memory");
    __builtin_amdgcn_s_barrier();
    asm volatile("" ::: "memory");

    int s0 = 0, s1 = 1, s2 = 2;
    for (int t = 0; t < nt; ++t) {
        short8 af[4][2], bfv[4][2];
#pragma unroll
        for (int kk = 0; kk < 2; kk++) {
            int c = kk * 4 + quad;
#pragma unroll
            for (int mi = 0; mi < 4; mi++) {
                int r = wm + mi * 16 + l16;
                af[mi][kk] = *(const short8*)&As[s0][r * 64 + ((c ^ (r & 7)) * 8)];
            }
#pragma unroll
            for (int ni = 0; ni < 4; ni++) {
                int r = wn + ni * 16 + l16;
                bfv[ni][kk] = *(const short8*)&Bs[s0][r * 64 + ((c ^ (r & 7)) * 8)];
            }
        }
        bool pf = (t + 2 < nt);
        if (pf) stage(t + 2, s2);
        __builtin_amdgcn_s_setprio(1);
#pragma unroll
        for (int kk = 0; kk < 2; kk++)
#pragma unroll
            for (int mi = 0; mi < 4; mi++)
#pragma unroll
                for (int ni = 0; ni < 4; ni++)
                    acc[mi][ni] = __builtin_amdgcn_mfma_f32_16x16x32_bf16(
                        af[mi][kk], bfv[ni][kk], acc[mi][ni], 0, 0, 0);
        __builtin_amdgcn_s_setprio(0);
        if (pf) asm volatile("s_waitcnt vmcnt(6)" ::: "memory");
        else    asm volatile("s_waitcnt vmcnt(0)" ::: "memory");
        __builtin_amdgcn_s_barrier();
        asm volatile("" ::: "memory");
        int tmp = s0; s0 = s1; s1 = s2; s2 = tmp;
    }

    int r4 = quad * 4;
#pragma unroll
    for (int mi = 0; mi < 4; mi++) {
#pragma unroll
        for (int ni = 0; ni < 4; ni++) {
#pragma unroll
            for (int r = 0; r < 4; r++) {
                int gm = m0 + wm + mi * 16 + r4 + r;
                int gn = n0 + wn + ni * 16 + l16;
                float v = acc[mi][ni][r];
                if (BIAS)  v += bias[gn];
                if (RESID) v += resid[(size_t)gm * Ndim + gn];
                if (RELU)  v = fmaxf(v, 0.f);
                if (OUTBF16) ((ushort*)Cout)[(size_t)gm * Ndim + gn] = f2bf(v);
                else         ((float*)Cout)[(size_t)gm * Ndim + gn] = v;
            }
        }
    }
}

// ---------------- causal flash attention: XCD-swizzled, dbuf glds, static-max softmax ----------------
// LDS 50.4 KB -> 3 blocks/CU (12 waves/CU): other blocks' MFMA covers this block's softmax VALU.
__global__ __launch_bounds__(256, 3) void attn_kernel(
    const ushort* __restrict__ qkv,
    const ushort* __restrict__ VtG,   // (h*256 + 4*d + b)*2048 + t
    ushort* __restrict__ attnb)
{
    const int LD = 3072;
    int bid = blockIdx.x;
    int bh = (bid & 7) * 8 + ((bid >> 3) & 7);
    int qt = 15 - (bid >> 6);
    int b = bh >> 4, h = bh & 15;
    int t0 = qt * 128;
    int tid = threadIdx.x;
    int wave = tid >> 6, lane = tid & 63;
    int quad = lane >> 4, l16 = lane & 15;

    __shared__ ushort Ks[2][64 * 64];
    __shared__ ushort Vt[2][64 * 64];
    __shared__ ushort Ps[4][32 * 72];

    const ushort* Qg = qkv + (size_t)(b * T_) * LD + h * 64;
    const ushort* Kg = Qg + 1024;
    const ushort* VtB = VtG + (size_t)(h * 256 + b) * T_;

    int qrow_base = t0 + wave * 32;
    int lrow = lane >> 3;
    int lchunk = (lane & 7) ^ (lrow & 7);

    short8 qa[2][2];
#pragma unroll
    for (int mt = 0; mt < 2; mt++) {
        const ushort* qp = Qg + (size_t)(qrow_base + mt * 16 + l16) * LD + quad * 8;
        ushort8 q0 = *(const ushort8*)qp;
        ushort8 q1 = *(const ushort8*)(qp + 32);
        ushort8 a0, a1;
#pragma unroll
        for (int d = 0; d < 8; d++) {
            a0[d] = f2bf(bf2f(q0[d]) * 0.03125f);
            a1[d] = f2bf(bf2f(q1[d]) * 0.03125f);
        }
        qa[mt][0] = __builtin_bit_cast(short8, a0);
        qa[mt][1] = __builtin_bit_cast(short8, a1);
    }

    float l_part[2][4];
    floatx4 o_acc[2][4];
#pragma unroll
    for (int mt = 0; mt < 2; mt++)
#pragma unroll
        for (int r = 0; r < 4; r++) {
            l_part[mt][r] = 0.f;
            o_acc[mt][r] = floatx4{0.f, 0.f, 0.f, 0.f};
        }

    int nIter = t0 / 64 + 2;

#pragma unroll
    for (int it = 0; it < 2; it++) {
        int rb = (wave * 2 + it) * 8;
        int r = rb + lrow;
        glds16(Kg  + (size_t)r * LD + lchunk * 8, &Ks[0][rb * 64]);
        glds16(VtB + (size_t)r * (4 * T_) + lchunk * 8, &Vt[0][rb * 64]);
    }

    for (int ii = 0; ii < nIter; ii++) {
        int s0 = ii * 64;
        int buf = ii & 1;
        __syncthreads();
        if (ii + 1 < nIter) {
            int sn = s0 + 64;
#pragma unroll
            for (int it = 0; it < 2; it++) {
                int rb = (wave * 2 + it) * 8;
                int r = rb + lrow;
                glds16(Kg  + (size_t)(sn + r) * LD + lchunk * 8, &Ks[buf ^ 1][rb * 64]);
                glds16(VtB + (size_t)r * (4 * T_) + sn + lchunk * 8, &Vt[buf ^ 1][rb * 64]);
            }
        }

        if (s0 <= qrow_base + 31) {
#pragma unroll
            for (int mt = 0; mt < 2; mt++) {
                floatx4 s_acc[4];
#pragma unroll
                for (int nt = 0; nt < 4; nt++) {
                    int krow = nt * 16 + l16;
                    const short8* kb0 = (const short8*)&Ks[buf][krow * 64 + ((quad       ^ (l16 & 7)) * 8)];
                    const short8* kb1 = (const short8*)&Ks[buf][krow * 64 + (((4 + quad) ^ (l16 & 7)) * 8)];
                    floatx4 z = {0.f, 0.f, 0.f, 0.f};
                    z = __builtin_amdgcn_mfma_f32_16x16x32_bf16(qa[mt][0], *kb0, z, 0, 0, 0);
                    s_acc[nt] = __builtin_amdgcn_mfma_f32_16x16x32_bf16(qa[mt][1], *kb1, z, 0, 0, 0);
                }
                int base_mt = qrow_base + mt * 16;
                if (s0 + 63 > base_mt) {
#pragma unroll
                    for (int nt = 0; nt < 4; nt++)
#pragma unroll
                        for (int r = 0; r < 4; r++) {
                            int gi = base_mt + quad * 4 + r;
                            int gj = s0 + nt * 16 + l16;
                            if (gj > gi) s_acc[nt][r] = -INFINITY;
                        }
                }
#pragma unroll
                for (int nt = 0; nt < 4; nt++)
#pragma unroll
                    for (int r = 0; r < 4; r++) {
                        float e = __expf(s_acc[nt][r]);
                        s_acc[nt][r] = e;
                        l_part[mt][r] += e;
                        Ps[wave][(mt * 16 + quad * 4 + r) * 72 + nt * 16 + l16] = f2bf(e);
                    }
            }
            asm volatile("s_waitcnt lgkmcnt(0)" ::: "memory");
            short8 pa[2][2];
#pragma unroll
            for (int mt = 0; mt < 2; mt++) {
                pa[mt][0] = *(const short8*)&Ps[wave][(mt * 16 + l16) * 72 + quad * 8];
                pa[mt][1] = *(const short8*)&Ps[wave][(mt * 16 + l16) * 72 + quad * 8 + 32];
            }
#pragma unroll
            for (int dt = 0; dt < 4; dt++) {
                int vrow = dt * 16 + l16;
                const short8* vb0 = (const short8*)&Vt[buf][vrow * 64 + ((quad       ^ (l16 & 7)) * 8)];
                const short8* vb1 = (const short8*)&Vt[buf][vrow * 64 + (((4 + quad) ^ (l16 & 7)) * 8)];
#pragma unroll
                for (int mt = 0; mt < 2; mt++) {
                    o_acc[mt][dt] = __builtin_amdgcn_mfma_f32_16x16x32_bf16(pa[mt][0], *vb0, o_acc[mt][dt], 0, 0, 0);
                    o_acc[mt][dt] = __builtin_amdgcn_mfma_f32_16x16x32_bf16(pa[mt][1], *vb1, o_acc[mt][dt], 0, 0, 0);
                }
            }
        }
    }

#pragma unroll
    for (int mt = 0; mt < 2; mt++)
#pragma unroll
        for (int r = 0; r < 4; r++) {
            float ls = l_part[mt][r];
            ls += __shfl_xor(ls, 1);
            ls += __shfl_xor(ls, 2);
            ls += __shfl_xor(ls, 4);
            ls += __shfl_xor(ls, 8);
            float inv = 1.f / ls;
            int gi = qrow_base + mt * 16 + quad * 4 + r;
            ushort* op = attnb + (size_t)(b * T_ + gi) * 1024 + h * 64;
#pragma unroll
            for (int dt = 0; dt < 4; dt++)
                op[dt * 16 + l16] = f2bf(o_acc[mt][dt][r] * inv);
        }
}

extern "C" void kernel_launch(void* const* d_in, const int* in_sizes, int n_in,
                              void* d_out, int out_size, void* d_ws, size_t ws_size,
                              hipStream_t stream) {
    (void)in_sizes; (void)n_in; (void)out_size; (void)ws_size;
    const float* x      = (const float*)d_in[0];
    const float* wq     = (const float*)d_in[1];
    const float* wk     = (const float*)d_in[2];
    const float* wv     = (const float*)d_in[3];
    const float* w_proj = (const float*)d_in[4];
    const float* b_proj = (const float*)d_in[5];
    const float* w1     = (const float*)d_in[6];
    const float* b1     = (const float*)d_in[7];
    const float* w2     = (const float*)d_in[8];
    const float* b2     = (const float*)d_in[9];
    const float* g1     = (const float*)d_in[10];
    const float* be1    = (const float*)d_in[11];
    const float* g2     = (const float*)d_in[12];
    const float* be2    = (const float*)d_in[13];
    float* out = (float*)d_out;

    char* ws = (char*)d_ws;
    const size_t MB = 1024ull * 1024ull;
    ushort* xn     = (ushort*)(ws + 0);        // 16 MB (reused as xn2 later)
    ushort* qkv    = (ushort*)(ws + 16 * MB);  // 48 MB
    ushort* attnb  = (ushort*)(ws + 64 * MB);  // 16 MB
    ushort* hbuf   = (ushort*)(ws + 16 * MB);  // 64 MB (aliases qkv+attnb, disjoint lifetime)
    float*  x1     = (float*) (ws + 80 * MB);  // 32 MB (written by proj, after attn)
    ushort* VtG    = (ushort*)(ws + 80 * MB);  // 16 MB (aliases x1; dead once proj runs)
    ushort* WqkvT  = (ushort*)(ws + 112 * MB); // 6 MB
    ushort* WprojT = (ushort*)(ws + 118 * MB); // 2 MB
    ushort* W1T    = (ushort*)(ws + 120 * MB); // 8 MB
    ushort* W2T    = (ushort*)(ws + 128 * MB); // 8 MB
    ushort* xn2 = xn;

    ln_kernel<<<M_, 256, 0, stream>>>(x, g1, be1, xn);
    // ALL six weight transposes in ONE launch (12288 tiles)
    transpose_all<<<12288, 256, 0, stream>>>(wq, wk, wv, w_proj, w1, w2,
                                             WqkvT, WprojT, W1T, W2T);
    // QKV: N=3072, gemm3b, grid 24x32=768
    gemm3b_kernel<true, false, false, false><<<dim3(3072 / 128, M_ / 256), 512, 0, stream>>>(
        xn, WqkvT, nullptr, nullptr, qkv, M_, 3072, C_);
    vtrans_kernel<<<dim3(T_ / 64, B_ * H_), 256, 0, stream>>>(qkv, VtG);
    attn_kernel<<<1024, 256, 0, stream>>>(qkv, VtG, attnb);
    // proj: N=1024, gemm3b, grid 8x32=256
    gemm3b_kernel<false, true, false, true><<<dim3(C_ / 128, M_ / 256), 512, 0, stream>>>(
        attnb, WprojT, b_proj, x, x1, M_, C_, C_);
    ln_kernel<<<M_, 256, 0, stream>>>(x1, g2, be2, xn2);
    // FFN1: N=4096, gemm3b (R5 best config), grid 32x32=1024
    gemm3b_kernel<true, true, true, false><<<dim3(4 * C_ / 128, M_ / 256), 512, 0, stream>>>(
        xn2, W1T, b1, nullptr, hbuf, M_, 4 * C_, C_);
    // FFN2: N=1024, K=4096, gemm3b, grid 8x32=256
    gemm3b_kernel<false, true, false, true><<<dim3(C_ / 128, M_ / 256), 512, 0, stream>>>(
        hbuf, W2T, b2, x1, out, M_, C_, 4 * C_);
}